// Round 3
// baseline (282.469 us; speedup 1.0000x reference)
//
#include <hip/hip_runtime.h>

#define N_COLS 24576
#define KSEL 64
#define NBINS 2048
#define NSUB 4
#define CAP 1024
#define TPB 1024
#define F4_PER_THREAD 6   // 24576 / 4 / 1024

__device__ __forceinline__ unsigned toSortable(float x) {
    unsigned u = __float_as_uint(x);
    return (u & 0x80000000u) ? ~u : (u | 0x80000000u);
}
__device__ __forceinline__ float fromSortable(unsigned s) {
    unsigned u = (s & 0x80000000u) ? (s & 0x7FFFFFFFu) : ~s;
    return __uint_as_float(u);
}

extern "C" __global__ void __launch_bounds__(TPB, 4)
topk_relu_kernel(const float* __restrict__ x, float* __restrict__ out) {
    __shared__ unsigned keys[N_COLS];            // 96 KB — row staged as sortable keys
    __shared__ unsigned hist[NSUB][NBINS];       // 32 KB
    __shared__ unsigned cand_s[CAP];             //  4 KB
    __shared__ unsigned short cand_i[CAP];       //  2 KB
    __shared__ int cand_cnt;
    __shared__ int sh_b1, sh_g;

    const int tid = threadIdx.x;
    const int row = blockIdx.x;
    const float4* __restrict__ xr = (const float4*)(x + (size_t)row * N_COLS);
    float4* __restrict__ outr = (float4*)(out + (size_t)row * N_COLS);

    // zero LDS histograms + counter
    #pragma unroll
    for (int i = 0; i < (NSUB * NBINS) / TPB; ++i)
        ((unsigned*)hist)[tid + i * TPB] = 0u;
    if (tid == 0) cand_cnt = 0;
    __syncthreads();

    unsigned* myh = hist[(tid >> 6) & (NSUB - 1)];

    // ---- pass 1: read x ONCE, stage keys in LDS, histogram top-11 bits ----
    #pragma unroll
    for (int j = 0; j < F4_PER_THREAD; ++j) {
        int f = j * TPB + tid;
        float4 v = xr[f];
        uint4 k;
        k.x = toSortable(v.x);
        k.y = toSortable(v.y);
        k.z = toSortable(v.z);
        k.w = toSortable(v.w);
        ((uint4*)keys)[f] = k;                  // ds_write_b128, contiguous
        atomicAdd(&myh[k.x >> 21], 1u);
        atomicAdd(&myh[k.y >> 21], 1u);
        atomicAdd(&myh[k.z >> 21], 1u);
        atomicAdd(&myh[k.w >> 21], 1u);
    }
    __syncthreads();

    // ---- reduce NSUB sub-histograms into hist[0] ----
    #pragma unroll
    for (int i = 0; i < NBINS / TPB; ++i) {
        int bin = tid + i * TPB;
        hist[0][bin] = hist[0][bin] + hist[1][bin] + hist[2][bin] + hist[3][bin];
    }
    __syncthreads();

    // ---- find threshold bin b1 and g = count strictly above it (wave 0) ----
    if (tid < 64) {
        unsigned running = 0;
        for (int c = NBINS / 64 - 1; c >= 0; --c) {
            int bin = c * 64 + tid;
            unsigned cnt = hist[0][bin];
            unsigned incl = cnt;
            #pragma unroll
            for (int d = 1; d < 64; d <<= 1) {
                unsigned o = __shfl_up(incl, d, 64);
                if (tid >= d) incl += o;
            }
            unsigned total = __shfl(incl, 63, 64);
            unsigned gt = running + (total - incl);   // # elements strictly above bin
            bool cond = (gt < KSEL) && (gt + cnt >= KSEL);
            unsigned long long m = __ballot(cond);
            if (m != 0ULL) {
                if (cond) { sh_b1 = bin; sh_g = (int)gt; }
                break;
            }
            running += total;
        }
    }
    __syncthreads();

    const int b1 = sh_b1;
    const int g  = sh_g;

    // ---- pass 2: keys from LDS -> output (relu / 0), gather candidates ----
    #pragma unroll
    for (int j = 0; j < F4_PER_THREAD; ++j) {
        int f = j * TPB + tid;
        uint4 k = ((const uint4*)keys)[f];
        float4 o;

        #define PROC(comp, e)                                                     \
        {                                                                         \
            unsigned s = k.comp;                                                  \
            int b = (int)(s >> 21);                                               \
            float r = 0.0f;                                                       \
            if (b > b1) {                                                         \
                float vv = fromSortable(s);                                       \
                r = vv > 0.0f ? vv : 0.0f;                                        \
            } else if (b == b1) {                                                 \
                int p = atomicAdd(&cand_cnt, 1);                                  \
                if (p < CAP) {                                                    \
                    cand_s[p] = s;                                                \
                    cand_i[p] = (unsigned short)(f * 4 + e);                      \
                }                                                                 \
            }                                                                     \
            o.comp = r;                                                           \
        }

        PROC(x, 0)
        PROC(y, 1)
        PROC(z, 2)
        PROC(w, 3)
        #undef PROC

        outr[f] = o;    // plain store — nt-store doubled WRITE_SIZE (round 2)
    }
    __syncthreads();   // drains stores (vmcnt) + candidate list complete

    // ---- exact rank-select among candidates, scatter selected relu values ----
    int C = cand_cnt;
    if (C > CAP) C = CAP;
    const int k1 = KSEL - g;   // how many to take from bin b1
    for (int i = tid; i < C; i += TPB) {
        unsigned si = cand_s[i];
        unsigned ii = cand_i[i];
        unsigned long long key_i =
            ((unsigned long long)si << 15) | (unsigned long long)(24575 - (int)ii);
        int rank = 0;
        for (int j = 0; j < C; ++j) {
            unsigned long long key_j =
                ((unsigned long long)cand_s[j] << 15) |
                (unsigned long long)(24575 - (int)cand_i[j]);
            rank += (key_j > key_i) ? 1 : 0;
        }
        if (rank < k1) {
            float vv = fromSortable(si);
            out[(size_t)row * N_COLS + ii] = vv > 0.0f ? vv : 0.0f;
        }
    }
}

extern "C" void kernel_launch(void* const* d_in, const int* in_sizes, int n_in,
                              void* d_out, int out_size, void* d_ws, size_t ws_size,
                              hipStream_t stream) {
    const float* x = (const float*)d_in[0];
    float* out = (float*)d_out;
    const int rows = in_sizes[0] / N_COLS;
    topk_relu_kernel<<<rows, TPB, 0, stream>>>(x, out);
}

// Round 4
// 193.368 us; speedup vs baseline: 1.4608x; 1.4608x over previous
//
#include <hip/hip_runtime.h>

#define N_COLS 24576
#define KSEL 64
#define TPB 256
#define F4T (N_COLS / 4 / TPB)   // 24 float4 per thread
#define CAP 512
#define NBINS 2048
#define PRE_F 2.4f               // static prefilter; 64th-largest of N(0,1) row ~2.79±0.04

__device__ __forceinline__ unsigned toSortable(float x) {
    unsigned u = __float_as_uint(x);
    return (u & 0x80000000u) ? ~u : (u | 0x80000000u);
}
__device__ __forceinline__ float fromSortable(unsigned s) {
    unsigned u = (s & 0x80000000u) ? (s & 0x7FFFFFFFu) : ~s;
    return __uint_as_float(u);
}

extern "C" __global__ void __launch_bounds__(TPB, 8)
topk_relu_kernel(const float* __restrict__ x, float* __restrict__ out) {
    __shared__ unsigned long long cand[CAP];   // key = (sortable<<15) | (24575-idx)
    __shared__ unsigned hist[NBINS];           // fallback only
    __shared__ int cand_cnt;
    __shared__ int sh_b1, sh_g;

    const int tid = threadIdx.x;
    const int row = blockIdx.x;
    const float4* __restrict__ xr = (const float4*)(x + (size_t)row * N_COLS);
    float4* __restrict__ outr = (float4*)(out + (size_t)row * N_COLS);

    if (tid == 0) cand_cnt = 0;
    __syncthreads();

    // ---- pass 1: stream read x, stream write zeros, collect rare candidates ----
    const float4 z4 = {0.0f, 0.0f, 0.0f, 0.0f};
    #pragma unroll 6
    for (int j = 0; j < F4T; ++j) {
        int f = j * TPB + tid;
        float4 v = xr[f];
        outr[f] = z4;                        // independent of load — overlaps fully

        #define PREF(comp, e)                                                     \
        if (v.comp > PRE_F) {                                                     \
            int p = atomicAdd(&cand_cnt, 1);                                      \
            if (p < CAP) {                                                        \
                unsigned s = toSortable(v.comp);                                  \
                cand[p] = ((unsigned long long)s << 15) |                         \
                          (unsigned long long)(24575 - (f * 4 + e));              \
            }                                                                     \
        }
        PREF(x, 0) PREF(y, 1) PREF(z, 2) PREF(w, 3)
        #undef PREF
    }
    __syncthreads();   // zero-stores drained (vmcnt) + candidate list complete

    int C = cand_cnt;
    if (C >= KSEL && C <= CAP) {
        // ---- fast exact path: rank-select top-64 among candidates ----
        // All excluded elements are <= PRE_F < every candidate, so top-64 of
        // candidates == top-64 of the row. Tie-break: (value desc, index asc).
        for (int i = tid; i < C; i += TPB) {
            unsigned long long ki = cand[i];
            int rank = 0;
            for (int j = 0; j < C; ++j)
                rank += (cand[j] > ki) ? 1 : 0;   // broadcast LDS read
            if (rank < KSEL) {
                int idx = 24575 - (int)(ki & 0x7FFFULL);
                float v = fromSortable((unsigned)(ki >> 15));
                out[(size_t)row * N_COLS + idx] = v > 0.0f ? v : 0.0f;
            }
        }
        return;
    }

    // ---- fallback: exact histogram select (not taken for N(0,1) input) ----
    for (int i = tid; i < NBINS; i += TPB) hist[i] = 0u;
    if (tid == 0) cand_cnt = 0;
    __syncthreads();

    for (int j = 0; j < F4T; ++j) {
        int f = j * TPB + tid;
        float4 v = xr[f];
        atomicAdd(&hist[toSortable(v.x) >> 21], 1u);
        atomicAdd(&hist[toSortable(v.y) >> 21], 1u);
        atomicAdd(&hist[toSortable(v.z) >> 21], 1u);
        atomicAdd(&hist[toSortable(v.w) >> 21], 1u);
    }
    __syncthreads();

    if (tid < 64) {
        unsigned running = 0;
        for (int c = NBINS / 64 - 1; c >= 0; --c) {
            int bin = c * 64 + tid;
            unsigned cnt = hist[bin];
            unsigned incl = cnt;
            #pragma unroll
            for (int d = 1; d < 64; d <<= 1) {
                unsigned o = __shfl_up(incl, d, 64);
                if (tid >= d) incl += o;
            }
            unsigned total = __shfl(incl, 63, 64);
            unsigned gt = running + (total - incl);
            bool cond = (gt < KSEL) && (gt + cnt >= KSEL);
            unsigned long long m = __ballot(cond);
            if (m != 0ULL) {
                if (cond) { sh_b1 = bin; sh_g = (int)gt; }
                break;
            }
            running += total;
        }
    }
    __syncthreads();

    const int b1 = sh_b1;
    const int g  = sh_g;

    for (int j = 0; j < F4T; ++j) {
        int f = j * TPB + tid;
        float4 v = xr[f];
        #define FPROC(comp, e)                                                    \
        {                                                                         \
            unsigned s = toSortable(v.comp);                                      \
            int b = (int)(s >> 21);                                               \
            if (b > b1) {                                                         \
                float vv = v.comp > 0.0f ? v.comp : 0.0f;                         \
                out[(size_t)row * N_COLS + f * 4 + e] = vv;                       \
            } else if (b == b1) {                                                 \
                int p = atomicAdd(&cand_cnt, 1);                                  \
                if (p < CAP) {                                                    \
                    cand[p] = ((unsigned long long)s << 15) |                     \
                              (unsigned long long)(24575 - (f * 4 + e));          \
                }                                                                 \
            }                                                                     \
        }
        FPROC(x, 0) FPROC(y, 1) FPROC(z, 2) FPROC(w, 3)
        #undef FPROC
    }
    __syncthreads();

    int C2 = cand_cnt;
    if (C2 > CAP) C2 = CAP;
    const int k1 = KSEL - g;
    for (int i = tid; i < C2; i += TPB) {
        unsigned long long ki = cand[i];
        int rank = 0;
        for (int j = 0; j < C2; ++j)
            rank += (cand[j] > ki) ? 1 : 0;
        if (rank < k1) {
            int idx = 24575 - (int)(ki & 0x7FFFULL);
            float v = fromSortable((unsigned)(ki >> 15));
            out[(size_t)row * N_COLS + idx] = v > 0.0f ? v : 0.0f;
        }
    }
}

extern "C" void kernel_launch(void* const* d_in, const int* in_sizes, int n_in,
                              void* d_out, int out_size, void* d_ws, size_t ws_size,
                              hipStream_t stream) {
    const float* x = (const float*)d_in[0];
    float* out = (float*)d_out;
    const int rows = in_sizes[0] / N_COLS;
    topk_relu_kernel<<<rows, TPB, 0, stream>>>(x, out);
}